// Round 6
// baseline (104.666 us; speedup 1.0000x reference)
//
#include <hip/hip_runtime.h>
#include <math.h>
#include <float.h>

#define N_PTS  1024
#define F_IN   512
#define F_OUT  128

typedef __bf16 b16x8 __attribute__((ext_vector_type(8)));
typedef float  f32x4 __attribute__((ext_vector_type(4)));

__device__ __forceinline__ unsigned short bf16_bits(float x) {
    union { __bf16 b; unsigned short u; } c; c.b = (__bf16)x; return c.u;
}

// ---------------- K1: h = inp@W + b -> hb (bf16 packed), norms ----------------
// grid 256 x 512 thr; 4 rows/block; 16-way k-split; float4 W loads.
// Visibility to K2 comes from the dispatch boundary. Block 0 also zeroes the
// completion counter used by K2's last-block finalize.
__global__ __launch_bounds__(512) void linear_kernel(
    const float* __restrict__ inp, const float* __restrict__ W,
    const float* __restrict__ bias, unsigned int* __restrict__ hbu,
    float* __restrict__ norms, unsigned int* __restrict__ counter)
{
    __shared__ float s_in[4 * F_IN];          // 8 KB
    __shared__ float s_part2[16][4][F_OUT];   // 32 KB
    __shared__ float s_h[4][F_OUT];           // 2 KB
    __shared__ float s_red[4][F_OUT];         // 2 KB

    const int tid  = threadIdx.x;
    const int row0 = blockIdx.x * 4;

    if (blockIdx.x == 0 && tid == 0) *counter = 0u;   // plain store; flushed at dispatch end

    ((float4*)s_in)[tid] = ((const float4*)(inp + row0 * F_IN))[tid];  // 512 x 16B
    __syncthreads();
    {
        const int f4 = tid & 31;      // float4 column group
        const int ks = tid >> 5;      // k-split 0..15 (32 k each)
        const float4* W4 = (const float4*)W;   // [512][32]
        float4 acc0 = {0,0,0,0}, acc1 = {0,0,0,0}, acc2 = {0,0,0,0}, acc3 = {0,0,0,0};
        const int kb = ks * 32;
        #pragma unroll 4
        for (int kk = 0; kk < 32; kk++) {
            const int k = kb + kk;
            const float4 w = W4[k * 32 + f4];      // coalesced 16B/lane
            const float a0 = s_in[0 * F_IN + k];   // LDS broadcast
            const float a1 = s_in[1 * F_IN + k];
            const float a2 = s_in[2 * F_IN + k];
            const float a3 = s_in[3 * F_IN + k];
            acc0.x = fmaf(a0, w.x, acc0.x); acc0.y = fmaf(a0, w.y, acc0.y);
            acc0.z = fmaf(a0, w.z, acc0.z); acc0.w = fmaf(a0, w.w, acc0.w);
            acc1.x = fmaf(a1, w.x, acc1.x); acc1.y = fmaf(a1, w.y, acc1.y);
            acc1.z = fmaf(a1, w.z, acc1.z); acc1.w = fmaf(a1, w.w, acc1.w);
            acc2.x = fmaf(a2, w.x, acc2.x); acc2.y = fmaf(a2, w.y, acc2.y);
            acc2.z = fmaf(a2, w.z, acc2.z); acc2.w = fmaf(a2, w.w, acc2.w);
            acc3.x = fmaf(a3, w.x, acc3.x); acc3.y = fmaf(a3, w.y, acc3.y);
            acc3.z = fmaf(a3, w.z, acc3.z); acc3.w = fmaf(a3, w.w, acc3.w);
        }
        *(float4*)&s_part2[ks][0][f4 * 4] = acc0;
        *(float4*)&s_part2[ks][1][f4 * 4] = acc1;
        *(float4*)&s_part2[ks][2][f4 * 4] = acc2;
        *(float4*)&s_part2[ks][3][f4 * 4] = acc3;
    }
    __syncthreads();
    {
        const int r = tid >> 7, f = tid & 127;
        float h = 0.f;
        #pragma unroll
        for (int ks = 0; ks < 16; ks++) h += s_part2[ks][r][f];
        h += bias[f];
        s_h[r][f]   = h;
        s_red[r][f] = h * h;
    }
    __syncthreads();
    if (tid < 128) {         // norms: 4 rows x 128 cols
        const int r = tid >> 5, c = tid & 31;
        float v = s_red[r][c] + s_red[r][c + 32] + s_red[r][c + 64] + s_red[r][c + 96];
        v += __shfl_xor(v, 1);  v += __shfl_xor(v, 2);  v += __shfl_xor(v, 4);
        v += __shfl_xor(v, 8);  v += __shfl_xor(v, 16);
        if (c == 0) norms[row0 + r] = v;
    } else if (tid >= 256) { // pack h -> bf16 pairs
        const int idx = tid - 256;          // 0..255
        const int r = idx >> 6, fp = idx & 63;
        const unsigned int lo = bf16_bits(s_h[r][fp * 2]);
        const unsigned int hi = bf16_bits(s_h[r][fp * 2 + 1]);
        hbu[(row0 + r) * 64 + fp] = lo | (hi << 16);
    }
}

// ---------------- K2: MFMA Gram (256-block strip shape, full parallelism) ->
//                      per-strip partials; LAST block (of 256) folds in K3 ----
// grid 256 (64 i-tiles x 4 j-strips) x 512 thr. Strip shape identical to the
// 71.9us baseline K2 (that shape is known-fast); finalize identical to old K3
// (same fp add order -> bitwise-identical output). Last-block pattern verified
// correct in round 4 (absmax 0.0).
__global__ __launch_bounds__(512) void gram_finalize_kernel(
    const unsigned int* __restrict__ hbu, const float* __restrict__ norms,
    const int* __restrict__ targets, float* __restrict__ pmaxp,
    float* __restrict__ pminp, unsigned int* __restrict__ counter,
    float* __restrict__ out)
{
    __shared__ float s_wmax[8][16];
    __shared__ float s_wmin[8][16];
    __shared__ float s_fin[8];
    __shared__ unsigned int s_last;

    const __bf16* hb = (const __bf16*)hbu;
    const int tid = threadIdx.x;
    const int b   = blockIdx.x;
    const int it  = b >> 2;            // i-tile 0..63
    const int js  = b & 3;             // j-strip 0..3
    const int i0  = it * 16;
    const int j0  = js * 256;
    const int w   = tid >> 6, l = tid & 63;
    const int q   = l >> 4,  lrow = l & 15;

    // A-frag: A[m=lane&15][k=quad*8+j] (HW-verified layout)
    const __bf16* aptr = hb + (i0 + lrow) * F_OUT + q * 8;
    b16x8 af[4];
    #pragma unroll
    for (int kk = 0; kk < 4; kk++) af[kk] = *(const b16x8*)(aptr + kk * 32);

    float ni[4]; int tcls[4];
    #pragma unroll
    for (int rg = 0; rg < 4; rg++) {
        ni[rg]   = norms[i0 + q * 4 + rg];
        tcls[rg] = targets[i0 + q * 4 + rg];
    }

    float pm[4] = {-FLT_MAX, -FLT_MAX, -FLT_MAX, -FLT_MAX};
    float pn[4] = { FLT_MAX,  FLT_MAX,  FLT_MAX,  FLT_MAX};

    #pragma unroll
    for (int jt = 0; jt < 2; jt++) {          // wave covers 32 j = 2 MFMA tiles
        const int jb = j0 + w * 32 + jt * 16;
        const __bf16* bptr = hb + (jb + lrow) * F_OUT + q * 8;
        f32x4 acc = {0.f, 0.f, 0.f, 0.f};
        #pragma unroll
        for (int kk = 0; kk < 4; kk++) {
            b16x8 bf = *(const b16x8*)(bptr + kk * 32);
            acc = __builtin_amdgcn_mfma_f32_16x16x32_bf16(af[kk], bf, acc, 0, 0, 0);
        }
        // C/D layout: col = lane&15 (j), row = quad*4 + reg (i)
        const int   gj = jb + lrow;
        const float nj = norms[gj];
        const int   tj = targets[gj];
        #pragma unroll
        for (int rg = 0; rg < 4; rg++) {
            const int gi = i0 + q * 4 + rg;
            const float d = fmaxf(fmaf(-2.f, acc[rg], ni[rg] + nj), 0.f);
            if (tcls[rg] == tj) { if (gi != gj) pm[rg] = fmaxf(pm[rg], d); }
            else                pn[rg] = fminf(pn[rg], d);
        }
    }
    #pragma unroll
    for (int rg = 0; rg < 4; rg++) {
        #pragma unroll
        for (int off = 1; off < 16; off <<= 1) {
            pm[rg] = fmaxf(pm[rg], __shfl_xor(pm[rg], off));
            pn[rg] = fminf(pn[rg], __shfl_xor(pn[rg], off));
        }
    }
    if (lrow == 0) {
        #pragma unroll
        for (int rg = 0; rg < 4; rg++) {
            s_wmax[w][q * 4 + rg] = pm[rg];
            s_wmin[w][q * 4 + rg] = pn[rg];
        }
    }
    __syncthreads();
    if (tid < 16) {      // combine 8 waves -> per-strip partial, plain store
        float M = -FLT_MAX, m = FLT_MAX;
        #pragma unroll
        for (int ww = 0; ww < 8; ww++) {
            M = fmaxf(M, s_wmax[ww][tid]);
            m = fminf(m, s_wmin[ww][tid]);
        }
        pmaxp[js * N_PTS + i0 + tid] = M;
        pminp[js * N_PTS + i0 + tid] = m;
    }

    // ---- last-block finalize (device-scope; pattern verified in round 4) ----
    __threadfence();          // release: storing threads (tid<16) flush partials
    __syncthreads();          // all stores + fences block-wide done
    if (tid == 0) s_last = (atomicAdd(counter, 1u) == 255u) ? 1u : 0u;
    __syncthreads();
    if (s_last) {             // block-uniform branch
        __threadfence();      // acquire: invalidate stale lines before reading
        float sum = 0.f;
        #pragma unroll
        for (int s = 0; s < 2; s++) {
            const int a = tid + s * 512;
            float hp = -FLT_MAX, hn = FLT_MAX;
            #pragma unroll
            for (int k = 0; k < 4; k++) {
                hp = fmaxf(hp, pmaxp[k * N_PTS + a]);
                hn = fminf(hn, pminp[k * N_PTS + a]);
            }
            if (hp >= 0.f) {   // hp = -FLT_MAX when no positive exists -> softplus(-inf)=0
                const float x = sqrtf(hp) - sqrtf(hn);
                sum += fmaxf(x, 0.f) + log1pf(expf(-fabsf(x)));
            }
        }
        #pragma unroll
        for (int off = 1; off < 64; off <<= 1) sum += __shfl_xor(sum, off);
        if (l == 0) s_fin[w] = sum;
        __syncthreads();
        if (tid == 0) {
            float t = 0.f;
            #pragma unroll
            for (int k = 0; k < 8; k++) t += s_fin[k];
            out[0] = t;
        }
    }
}

extern "C" void kernel_launch(void* const* d_in, const int* in_sizes, int n_in,
                              void* d_out, int out_size, void* d_ws, size_t ws_size,
                              hipStream_t stream) {
    const float* inp     = (const float*)d_in[0];
    const int*   targets = (const int*)d_in[1];
    const float* W       = (const float*)d_in[2];
    const float* bias    = (const float*)d_in[3];

    char* base = (char*)d_ws;
    unsigned int* hbu     = (unsigned int*)base;                  // 256 KB (bf16 h, packed)
    float*        norms   = (float*)(base + (256 << 10));         // 4 KB
    float*        pmaxp   = (float*)(base + (260 << 10));         // 16 KB
    float*        pminp   = (float*)(base + (276 << 10));         // 16 KB
    unsigned int* counter = (unsigned int*)(base + (292 << 10));  // 4 B

    linear_kernel<<<256, 512, 0, stream>>>(inp, W, bias, hbu, norms, counter);
    gram_finalize_kernel<<<256, 512, 0, stream>>>(hbu, norms, targets, pmaxp,
                                                  pminp, counter, (float*)d_out);
}

// Round 7
// 73.487 us; speedup vs baseline: 1.4243x; 1.4243x over previous
//
#include <hip/hip_runtime.h>
#include <math.h>
#include <float.h>

#define N_PTS  1024
#define F_IN   512
#define F_OUT  128

typedef __bf16 b16x8 __attribute__((ext_vector_type(8)));
typedef float  f32x4 __attribute__((ext_vector_type(4)));

__device__ __forceinline__ unsigned short bf16_bits(float x) {
    union { __bf16 b; unsigned short u; } c; c.b = (__bf16)x; return c.u;
}

// Monotonic map for NON-NEGATIVE floats: order-preserving into unsigned.
// (All real distances are >= 0 after the fmaxf(...,0) clamp; sentinels skipped.)
__device__ __forceinline__ unsigned int fmap_nn(float f) {
    union { float f; unsigned int u; } c; c.f = f;
    return c.u | 0x80000000u;
}
__device__ __forceinline__ float funmap_nn(unsigned int u) {
    union { float f; unsigned int u; } c; c.u = u & 0x7FFFFFFFu;
    return c.f;
}

// ---------------- K1: h = inp@W + b -> hb (bf16 packed), norms ----------------
// grid 256 x 512 thr; 4 rows/block; 16-way k-split; float4 W loads.
// Block 0 also inits the K2 combine state (counter=0, hpM=0, hnM=~0).
// Visibility to K2 comes from the dispatch-boundary flush (plain stores ok).
__global__ __launch_bounds__(512) void linear_kernel(
    const float* __restrict__ inp, const float* __restrict__ W,
    const float* __restrict__ bias, unsigned int* __restrict__ hbu,
    float* __restrict__ norms, unsigned int* __restrict__ hpM,
    unsigned int* __restrict__ hnM, unsigned int* __restrict__ counter)
{
    __shared__ float s_in[4 * F_IN];          // 8 KB
    __shared__ float s_part2[16][4][F_OUT];   // 32 KB
    __shared__ float s_h[4][F_OUT];           // 2 KB
    __shared__ float s_red[4][F_OUT];         // 2 KB

    const int tid  = threadIdx.x;
    const int row0 = blockIdx.x * 4;

    if (blockIdx.x == 0) {                    // init combine state (plain stores)
        if (tid == 0) *counter = 0u;
        hpM[tid]       = 0u;          hpM[tid + 512] = 0u;          // identity for umax
        hnM[tid]       = 0xFFFFFFFFu; hnM[tid + 512] = 0xFFFFFFFFu; // identity for umin
    }

    ((float4*)s_in)[tid] = ((const float4*)(inp + row0 * F_IN))[tid];  // 512 x 16B
    __syncthreads();
    {
        const int f4 = tid & 31;      // float4 column group
        const int ks = tid >> 5;      // k-split 0..15 (32 k each)
        const float4* W4 = (const float4*)W;   // [512][32]
        float4 acc0 = {0,0,0,0}, acc1 = {0,0,0,0}, acc2 = {0,0,0,0}, acc3 = {0,0,0,0};
        const int kb = ks * 32;
        #pragma unroll 4
        for (int kk = 0; kk < 32; kk++) {
            const int k = kb + kk;
            const float4 w = W4[k * 32 + f4];      // coalesced 16B/lane
            const float a0 = s_in[0 * F_IN + k];   // LDS broadcast
            const float a1 = s_in[1 * F_IN + k];
            const float a2 = s_in[2 * F_IN + k];
            const float a3 = s_in[3 * F_IN + k];
            acc0.x = fmaf(a0, w.x, acc0.x); acc0.y = fmaf(a0, w.y, acc0.y);
            acc0.z = fmaf(a0, w.z, acc0.z); acc0.w = fmaf(a0, w.w, acc0.w);
            acc1.x = fmaf(a1, w.x, acc1.x); acc1.y = fmaf(a1, w.y, acc1.y);
            acc1.z = fmaf(a1, w.z, acc1.z); acc1.w = fmaf(a1, w.w, acc1.w);
            acc2.x = fmaf(a2, w.x, acc2.x); acc2.y = fmaf(a2, w.y, acc2.y);
            acc2.z = fmaf(a2, w.z, acc2.z); acc2.w = fmaf(a2, w.w, acc2.w);
            acc3.x = fmaf(a3, w.x, acc3.x); acc3.y = fmaf(a3, w.y, acc3.y);
            acc3.z = fmaf(a3, w.z, acc3.z); acc3.w = fmaf(a3, w.w, acc3.w);
        }
        *(float4*)&s_part2[ks][0][f4 * 4] = acc0;
        *(float4*)&s_part2[ks][1][f4 * 4] = acc1;
        *(float4*)&s_part2[ks][2][f4 * 4] = acc2;
        *(float4*)&s_part2[ks][3][f4 * 4] = acc3;
    }
    __syncthreads();
    {
        const int r = tid >> 7, f = tid & 127;
        float h = 0.f;
        #pragma unroll
        for (int ks = 0; ks < 16; ks++) h += s_part2[ks][r][f];
        h += bias[f];
        s_h[r][f]   = h;
        s_red[r][f] = h * h;
    }
    __syncthreads();
    if (tid < 128) {         // norms: 4 rows x 128 cols
        const int r = tid >> 5, c = tid & 31;
        float v = s_red[r][c] + s_red[r][c + 32] + s_red[r][c + 64] + s_red[r][c + 96];
        v += __shfl_xor(v, 1);  v += __shfl_xor(v, 2);  v += __shfl_xor(v, 4);
        v += __shfl_xor(v, 8);  v += __shfl_xor(v, 16);
        if (c == 0) norms[row0 + r] = v;
    } else if (tid >= 256) { // pack h -> bf16 pairs
        const int idx = tid - 256;          // 0..255
        const int r = idx >> 6, fp = idx & 63;
        const unsigned int lo = bf16_bits(s_h[r][fp * 2]);
        const unsigned int hi = bf16_bits(s_h[r][fp * 2 + 1]);
        hbu[(row0 + r) * 64 + fp] = lo | (hi << 16);
    }
}

// ---------------- K2: MFMA Gram (256-block strip shape) -> atomic combine,
//                      last-block finalize. ZERO fences: all cross-block data
//                      moves through device-scope atomics (coherence point). ----
// grid 256 (64 i-tiles x 4 j-strips) x 512 thr.
__global__ __launch_bounds__(512) void gram_finalize_kernel(
    const unsigned int* __restrict__ hbu, const float* __restrict__ norms,
    const int* __restrict__ targets, unsigned int* __restrict__ hpM,
    unsigned int* __restrict__ hnM, unsigned int* __restrict__ counter,
    float* __restrict__ out)
{
    __shared__ float s_wmax[8][16];
    __shared__ float s_wmin[8][16];
    __shared__ float s_fin[8];
    __shared__ unsigned int s_last;

    const __bf16* hb = (const __bf16*)hbu;
    const int tid = threadIdx.x;
    const int b   = blockIdx.x;
    const int it  = b >> 2;            // i-tile 0..63
    const int js  = b & 3;             // j-strip 0..3
    const int i0  = it * 16;
    const int j0  = js * 256;
    const int w   = tid >> 6, l = tid & 63;
    const int q   = l >> 4,  lrow = l & 15;

    // A-frag: A[m=lane&15][k=quad*8+j] (HW-verified layout)
    const __bf16* aptr = hb + (i0 + lrow) * F_OUT + q * 8;
    b16x8 af[4];
    #pragma unroll
    for (int kk = 0; kk < 4; kk++) af[kk] = *(const b16x8*)(aptr + kk * 32);

    float ni[4]; int tcls[4];
    #pragma unroll
    for (int rg = 0; rg < 4; rg++) {
        ni[rg]   = norms[i0 + q * 4 + rg];
        tcls[rg] = targets[i0 + q * 4 + rg];
    }

    float pm[4] = {-FLT_MAX, -FLT_MAX, -FLT_MAX, -FLT_MAX};
    float pn[4] = { FLT_MAX,  FLT_MAX,  FLT_MAX,  FLT_MAX};

    #pragma unroll
    for (int jt = 0; jt < 2; jt++) {          // wave covers 32 j = 2 MFMA tiles
        const int jb = j0 + w * 32 + jt * 16;
        const __bf16* bptr = hb + (jb + lrow) * F_OUT + q * 8;
        f32x4 acc = {0.f, 0.f, 0.f, 0.f};
        #pragma unroll
        for (int kk = 0; kk < 4; kk++) {
            b16x8 bf = *(const b16x8*)(bptr + kk * 32);
            acc = __builtin_amdgcn_mfma_f32_16x16x32_bf16(af[kk], bf, acc, 0, 0, 0);
        }
        // C/D layout: col = lane&15 (j), row = quad*4 + reg (i)
        const int   gj = jb + lrow;
        const float nj = norms[gj];
        const int   tj = targets[gj];
        #pragma unroll
        for (int rg = 0; rg < 4; rg++) {
            const int gi = i0 + q * 4 + rg;
            const float d = fmaxf(fmaf(-2.f, acc[rg], ni[rg] + nj), 0.f);
            if (tcls[rg] == tj) { if (gi != gj) pm[rg] = fmaxf(pm[rg], d); }
            else                pn[rg] = fminf(pn[rg], d);
        }
    }
    #pragma unroll
    for (int rg = 0; rg < 4; rg++) {
        #pragma unroll
        for (int off = 1; off < 16; off <<= 1) {
            pm[rg] = fmaxf(pm[rg], __shfl_xor(pm[rg], off));
            pn[rg] = fminf(pn[rg], __shfl_xor(pn[rg], off));
        }
    }
    if (lrow == 0) {
        #pragma unroll
        for (int rg = 0; rg < 4; rg++) {
            s_wmax[w][q * 4 + rg] = pm[rg];
            s_wmin[w][q * 4 + rg] = pn[rg];
        }
    }
    __syncthreads();
    if (tid < 16) {      // combine 8 waves, then ATOMIC cross-strip combine
        float M = -FLT_MAX, m = FLT_MAX;
        #pragma unroll
        for (int ww = 0; ww < 8; ww++) {
            M = fmaxf(M, s_wmax[ww][tid]);
            m = fminf(m, s_wmin[ww][tid]);
        }
        // exact order-preserving unsigned map; sentinels (no pos / no neg) skipped
        if (M != -FLT_MAX) atomicMax(&hpM[i0 + tid], fmap_nn(M));
        if (m !=  FLT_MAX) atomicMin(&hnM[i0 + tid], fmap_nn(m));
    }
    if (tid == 0) {
        // wave-level wait: our wave's combine-atomics reached the coherence
        // point before the counter increment becomes visible.
        asm volatile("s_waitcnt vmcnt(0)" ::: "memory");
        s_last = (atomicAdd(counter, 1u) == 255u) ? 1u : 0u;
    }
    __syncthreads();
    if (s_last) {        // block-uniform; read fresh values via atomic RMW-reads
        float sum = 0.f;
        #pragma unroll
        for (int s = 0; s < 2; s++) {
            const int a = tid + s * 512;
            const unsigned int uM = atomicAdd(&hpM[a], 0u);   // fresh @ coherence pt
            const unsigned int um = atomicAdd(&hnM[a], 0u);
            if (uM != 0u) {  // 0 => no positive existed -> softplus(-inf)=0
                const float hp = funmap_nn(uM);
                const float hn = (um == 0xFFFFFFFFu) ? FLT_MAX : funmap_nn(um);
                const float x  = sqrtf(hp) - sqrtf(hn);
                sum += fmaxf(x, 0.f) + log1pf(expf(-fabsf(x)));
            }
        }
        #pragma unroll
        for (int off = 1; off < 64; off <<= 1) sum += __shfl_xor(sum, off);
        if (l == 0) s_fin[w] = sum;
        __syncthreads();
        if (tid == 0) {
            float t = 0.f;
            #pragma unroll
            for (int k = 0; k < 8; k++) t += s_fin[k];
            out[0] = t;
        }
    }
}

extern "C" void kernel_launch(void* const* d_in, const int* in_sizes, int n_in,
                              void* d_out, int out_size, void* d_ws, size_t ws_size,
                              hipStream_t stream) {
    const float* inp     = (const float*)d_in[0];
    const int*   targets = (const int*)d_in[1];
    const float* W       = (const float*)d_in[2];
    const float* bias    = (const float*)d_in[3];

    char* base = (char*)d_ws;
    unsigned int* hbu     = (unsigned int*)base;                  // 256 KB (bf16 h, packed)
    float*        norms   = (float*)(base + (256 << 10));         // 4 KB
    unsigned int* hpM     = (unsigned int*)(base + (260 << 10));  // 4 KB (mapped max)
    unsigned int* hnM     = (unsigned int*)(base + (264 << 10));  // 4 KB (mapped min)
    unsigned int* counter = (unsigned int*)(base + (268 << 10));  // 4 B

    linear_kernel<<<256, 512, 0, stream>>>(inp, W, bias, hbu, norms, hpM, hnM, counter);
    gram_finalize_kernel<<<256, 512, 0, stream>>>(hbu, norms, targets, hpM, hnM,
                                                  counter, (float*)d_out);
}